// Round 1
// baseline (1562.932 us; speedup 1.0000x reference)
//
#include <hip/hip_runtime.h>
#include <hip/hip_bf16.h>

#define N_NODES 30000
#define N_EDGES 480000
#define NFEAT 92
#define EFEAT 50
#define D1 64
#define ZD 178
#define NL 3
#define NG 256
#define BN_EPS 1e-5f

// ---------------- lin0: h = relu(x @ W0 + b0) ----------------
// wave = node, lane = output feature; W0 column held in 92 VGPRs/lane.
extern "C" __global__ void __launch_bounds__(256)
k_lin0(const float* __restrict__ x, const float* __restrict__ w,
       const float* __restrict__ b, float* __restrict__ h) {
  const int lane = threadIdx.x & 63;
  const int wave = (blockIdx.x * blockDim.x + threadIdx.x) >> 6;
  const int nw = (gridDim.x * blockDim.x) >> 6;
  float wreg[NFEAT];
#pragma unroll
  for (int k = 0; k < NFEAT; ++k) wreg[k] = w[k * D1 + lane];
  const float bj = b[lane];
  for (int i = wave; i < N_NODES; i += nw) {
    const float2* xr = (const float2*)(x + (size_t)i * NFEAT);
    float acc = bj;
#pragma unroll
    for (int k = 0; k < NFEAT / 2; ++k) {
      const float2 v = xr[k];  // same addr across wave -> L1 broadcast
      acc = fmaf(v.x, wreg[2 * k], acc);
      acc = fmaf(v.y, wreg[2 * k + 1], acc);
    }
    h[(size_t)i * D1 + lane] = fmaxf(acc, 0.0f);
  }
}

// ---------------- per-dst edge counts ----------------
extern "C" __global__ void __launch_bounds__(256)
k_cnt(const int* __restrict__ ei, float* __restrict__ cnt) {
  const int e = blockIdx.x * blockDim.x + threadIdx.x;
  if (e < N_EDGES) atomicAdd(&cnt[ei[N_EDGES + e]], 1.0f);
}

extern "C" __global__ void __launch_bounds__(256)
k_inv(const float* __restrict__ cnt, float* __restrict__ invc) {
  const int i = blockIdx.x * blockDim.x + threadIdx.x;
  if (i < N_NODES) invc[i] = 1.0f / fmaxf(cnt[i], 1.0f);
}

// ---------------- node projections ----------------
// P = h @ [Wf_rows0:64 | Wf_rows64:128 | Ws_rows0:64 | Ws_rows64:128]
// block = 4 waves; wave w owns one 64-col block, its W column in 64 VGPRs/lane.
// pf[n*128 + 0..63]  = (h @ Wf[0:64])[n]    (dst part)
// pf[n*128 + 64..127]= (h @ Wf[64:128])[n]  (src part); ps likewise for Ws.
extern "C" __global__ void __launch_bounds__(256)
k_nodeproj(const float* __restrict__ h, const float* __restrict__ wf,
           const float* __restrict__ wsm, float* __restrict__ pf,
           float* __restrict__ ps) {
  const int lane = threadIdx.x & 63;
  const int w = threadIdx.x >> 6;  // 0..3
  const float* W = (w < 2) ? wf : wsm;
  const int roff = (w & 1) * 64;
  float wreg[D1];
#pragma unroll
  for (int k = 0; k < D1; ++k) wreg[k] = W[(size_t)(roff + k) * D1 + lane];
  float* out = (w < 2) ? pf : ps;
  const int ooff = (w & 1) * 64;
  for (int i = blockIdx.x; i < N_NODES; i += gridDim.x) {
    const float4* hr = (const float4*)(h + (size_t)i * D1);
    float acc = 0.0f;
#pragma unroll
    for (int k4 = 0; k4 < D1 / 4; ++k4) {
      const float4 v = hr[k4];
      acc = fmaf(v.x, wreg[4 * k4 + 0], acc);
      acc = fmaf(v.y, wreg[4 * k4 + 1], acc);
      acc = fmaf(v.z, wreg[4 * k4 + 2], acc);
      acc = fmaf(v.w, wreg[4 * k4 + 3], acc);
    }
    out[(size_t)i * 128 + ooff + lane] = acc;
  }
}

// ---------------- edge kernel ----------------
// wave = edge, lane = output feature.
// a = pf[dst].dstpart + pf[src].srcpart + bias + edge_attr @ W2  (W2 in VGPRs)
// m = sigmoid(af) * softplus(as); atomic scatter-add into aggr[dst].
extern "C" __global__ void __launch_bounds__(256)
k_edge(const float* __restrict__ pf, const float* __restrict__ ps,
       const float* __restrict__ ea, const int* __restrict__ ei,
       const float* __restrict__ wf2, const float* __restrict__ ws2,
       const float* __restrict__ bf, const float* __restrict__ bs,
       float* __restrict__ aggr) {
  const int lane = threadIdx.x & 63;
  const int wave = (blockIdx.x * blockDim.x + threadIdx.x) >> 6;
  const int nw = (gridDim.x * blockDim.x) >> 6;
  float wf[EFEAT], wsr[EFEAT];
#pragma unroll
  for (int k = 0; k < EFEAT; ++k) {
    wf[k] = wf2[k * D1 + lane];
    wsr[k] = ws2[k * D1 + lane];
  }
  const float bfj = bf[lane], bsj = bs[lane];
  for (int e = wave; e < N_EDGES; e += nw) {
    const int s = ei[e];
    const int d = ei[N_EDGES + e];
    float af = pf[(size_t)d * 128 + lane] + pf[(size_t)s * 128 + 64 + lane] + bfj;
    float as = ps[(size_t)d * 128 + lane] + ps[(size_t)s * 128 + 64 + lane] + bsj;
    const float2* ear = (const float2*)(ea + (size_t)e * EFEAT);
#pragma unroll
    for (int k = 0; k < EFEAT / 2; ++k) {
      const float2 v = ear[k];  // wave-uniform addr -> broadcast
      af = fmaf(v.x, wf[2 * k], af);
      af = fmaf(v.y, wf[2 * k + 1], af);
      as = fmaf(v.x, wsr[2 * k], as);
      as = fmaf(v.y, wsr[2 * k + 1], as);
    }
    const float sg = __builtin_amdgcn_rcpf(1.0f + __expf(-af));
    const float sp = __logf(1.0f + __expf(as));
    atomicAdd(&aggr[(size_t)d * D1 + lane], sg * sp);
  }
}

// ---------------- BN stats: per-feature sum / sumsq of aggr*invc ----------------
extern "C" __global__ void __launch_bounds__(256)
k_stats(const float* __restrict__ aggr, const float* __restrict__ invc,
        float* __restrict__ musum, float* __restrict__ sqsum) {
  const int j = threadIdx.x & 63;
  const int rid = (blockIdx.x * blockDim.x + threadIdx.x) >> 6;
  const int rstr = (gridDim.x * blockDim.x) >> 6;
  float s = 0.0f, sq = 0.0f;
  for (int i = rid; i < N_NODES; i += rstr) {
    const float v = aggr[(size_t)i * D1 + j] * invc[i];
    s += v;
    sq = fmaf(v, v, sq);
  }
  __shared__ float ls[256], lq[256];
  ls[threadIdx.x] = s;
  lq[threadIdx.x] = sq;
  __syncthreads();
  if (threadIdx.x < 64) {
    s = ls[j] + ls[64 + j] + ls[128 + j] + ls[192 + j];
    sq = lq[j] + lq[64 + j] + lq[128 + j] + lq[192 + j];
    atomicAdd(&musum[j], s);
    atomicAdd(&sqsum[j], sq);
  }
}

extern "C" __global__ void __launch_bounds__(64)
k_bnfin(const float* __restrict__ musum, const float* __restrict__ sqsum,
        const float* __restrict__ gamma, const float* __restrict__ beta,
        float* __restrict__ rs, float* __restrict__ sh) {
  const int j = threadIdx.x;
  const float mu = musum[j] * (1.0f / N_NODES);
  const float var = sqsum[j] * (1.0f / N_NODES) - mu * mu;  // biased, as jnp.var
  const float r = gamma[j] * rsqrtf(var + BN_EPS);
  rs[j] = r;
  sh[j] = beta[j] - mu * r;
}

// ---------------- h = relu(h + bn(aggr_mean)) ----------------
extern "C" __global__ void __launch_bounds__(256)
k_update(float* __restrict__ h, const float* __restrict__ aggr,
         const float* __restrict__ invc, const float* __restrict__ rs,
         const float* __restrict__ sh) {
  const size_t idx = (size_t)blockIdx.x * blockDim.x + threadIdx.x;
  if (idx >= (size_t)N_NODES * D1) return;
  const int i = (int)(idx >> 6), j = (int)(idx & 63);
  const float bn = fmaf(aggr[idx] * invc[i], rs[j], sh[j]);
  h[idx] = fmaxf(h[idx] + bn, 0.0f);
}

// ---------------- global mean pool (atomic) ----------------
extern "C" __global__ void __launch_bounds__(256)
k_pool(const float* __restrict__ h, const int* __restrict__ batch,
       float* __restrict__ pooled, float* __restrict__ gcnt) {
  const int lane = threadIdx.x & 63;
  const int wave = (blockIdx.x * blockDim.x + threadIdx.x) >> 6;
  const int nw = (gridDim.x * blockDim.x) >> 6;
  for (int i = wave; i < N_NODES; i += nw) {
    const int b = batch[i];
    atomicAdd(&pooled[(size_t)b * D1 + lane], h[(size_t)i * D1 + lane]);
    if (lane == 0) atomicAdd(&gcnt[b], 1.0f);
  }
}

// ---------------- final MLP chain, one block (1 wave) per graph ----------------
extern "C" __global__ void __launch_bounds__(64)
k_mlp(const float* __restrict__ pooled, const float* __restrict__ gcnt,
      const float* __restrict__ lin1_w, const float* __restrict__ lin1_b,
      const float* __restrict__ fc_w, const float* __restrict__ fc_b,
      const float* __restrict__ lin2_w, const float* __restrict__ lin2_b,
      float* __restrict__ out) {
  const int g = blockIdx.x;
  const int j = threadIdx.x;
  __shared__ float vin[D1];
  const float inv = 1.0f / fmaxf(gcnt[g], 1.0f);
  float v = pooled[(size_t)g * D1 + j] * inv;
  for (int layer = 0; layer < 3; ++layer) {
    vin[j] = v;
    __syncthreads();
    const float* W;
    const float* B;
    if (layer == 0) {
      W = lin1_w;
      B = lin1_b;
    } else {
      W = fc_w + (size_t)(layer - 1) * D1 * D1;
      B = fc_b + (size_t)(layer - 1) * D1;
    }
    float acc = B[j];
#pragma unroll 16
    for (int k = 0; k < D1; ++k) acc = fmaf(vin[k], W[k * D1 + j], acc);
    v = fmaxf(acc, 0.0f);
    __syncthreads();
  }
  float p = v * lin2_w[j];
#pragma unroll
  for (int off = 32; off > 0; off >>= 1) p += __shfl_down(p, off);
  if (j == 0) out[g] = p + lin2_b[0];
}

extern "C" void kernel_launch(void* const* d_in, const int* in_sizes, int n_in,
                              void* d_out, int out_size, void* d_ws, size_t ws_size,
                              hipStream_t stream) {
  const float* x        = (const float*)d_in[0];
  const float* ea       = (const float*)d_in[1];
  const float* lin0_w   = (const float*)d_in[2];
  const float* lin0_b   = (const float*)d_in[3];
  const float* conv_wf  = (const float*)d_in[4];
  const float* conv_bf  = (const float*)d_in[5];
  const float* conv_ws  = (const float*)d_in[6];
  const float* conv_bs  = (const float*)d_in[7];
  const float* bn_gamma = (const float*)d_in[8];
  const float* bn_beta  = (const float*)d_in[9];
  const float* lin1_w   = (const float*)d_in[10];
  const float* lin1_b   = (const float*)d_in[11];
  const float* fc_w     = (const float*)d_in[12];
  const float* fc_b     = (const float*)d_in[13];
  const float* lin2_w   = (const float*)d_in[14];
  const float* lin2_b   = (const float*)d_in[15];
  const int*   ei       = (const int*)d_in[16];
  const int*   batch    = (const int*)d_in[17];

  float* wsp = (float*)d_ws;
  float* h      = wsp;                          // N*64
  float* pf     = h + (size_t)N_NODES * 64;     // N*128
  float* ps     = pf + (size_t)N_NODES * 128;   // N*128
  float* aggr   = ps + (size_t)N_NODES * 128;   // N*64
  float* musum  = aggr + (size_t)N_NODES * 64;  // 64
  float* sqsum  = musum + 64;                   // 64
  float* rs     = sqsum + 64;                   // 64
  float* sh     = rs + 64;                      // 64
  float* cnt    = sh + 64;                      // N
  float* invc   = cnt + N_NODES;                // N
  float* pooled = invc + N_NODES;               // G*64
  float* gcnt   = pooled + (size_t)NG * 64;     // G

  hipMemsetAsync(cnt, 0, N_NODES * sizeof(float), stream);
  hipMemsetAsync(pooled, 0, (NG * D1 + NG) * sizeof(float), stream);

  k_lin0<<<256, 256, 0, stream>>>(x, lin0_w, lin0_b, h);
  k_cnt<<<(N_EDGES + 255) / 256, 256, 0, stream>>>(ei, cnt);
  k_inv<<<(N_NODES + 255) / 256, 256, 0, stream>>>(cnt, invc);

  for (int l = 0; l < NL; ++l) {
    const float* wf  = conv_wf + (size_t)l * ZD * D1;
    const float* wsm = conv_ws + (size_t)l * ZD * D1;
    k_nodeproj<<<512, 256, 0, stream>>>(h, wf, wsm, pf, ps);
    hipMemsetAsync(aggr, 0, ((size_t)N_NODES * D1 + 128) * sizeof(float), stream);
    k_edge<<<2048, 256, 0, stream>>>(pf, ps, ea, ei, wf + 128 * D1, wsm + 128 * D1,
                                     conv_bf + (size_t)l * D1, conv_bs + (size_t)l * D1,
                                     aggr);
    k_stats<<<64, 256, 0, stream>>>(aggr, invc, musum, sqsum);
    k_bnfin<<<1, 64, 0, stream>>>(musum, sqsum, bn_gamma + (size_t)l * D1,
                                  bn_beta + (size_t)l * D1, rs, sh);
    k_update<<<(N_NODES * D1 + 255) / 256, 256, 0, stream>>>(h, aggr, invc, rs, sh);
  }

  k_pool<<<128, 256, 0, stream>>>(h, batch, pooled, gcnt);
  k_mlp<<<NG, 64, 0, stream>>>(pooled, gcnt, lin1_w, lin1_b, fc_w, fc_b,
                               lin2_w, lin2_b, (float*)d_out);
}

// Round 2
// 1156.230 us; speedup vs baseline: 1.3517x; 1.3517x over previous
//
#include <hip/hip_runtime.h>
#include <hip/hip_bf16.h>

#define N_NODES 30000
#define N_EDGES 480000
#define NFEAT 92
#define EFEAT 50
#define D1 64
#define ZD 178
#define NL 3
#define NG 256
#define BN_EPS 1e-5f

// ---------------- lin0: h = relu(x @ W0 + b0) ----------------
extern "C" __global__ void __launch_bounds__(256)
k_lin0(const float* __restrict__ x, const float* __restrict__ w,
       const float* __restrict__ b, float* __restrict__ h) {
  const int lane = threadIdx.x & 63;
  const int wave = (blockIdx.x * blockDim.x + threadIdx.x) >> 6;
  const int nw = (gridDim.x * blockDim.x) >> 6;
  float wreg[NFEAT];
#pragma unroll
  for (int k = 0; k < NFEAT; ++k) wreg[k] = w[k * D1 + lane];
  const float bj = b[lane];
  for (int i = wave; i < N_NODES; i += nw) {
    const float2* xr = (const float2*)(x + (size_t)i * NFEAT);
    float acc = bj;
#pragma unroll
    for (int k = 0; k < NFEAT / 2; ++k) {
      const float2 v = xr[k];
      acc = fmaf(v.x, wreg[2 * k], acc);
      acc = fmaf(v.y, wreg[2 * k + 1], acc);
    }
    h[(size_t)i * D1 + lane] = fmaxf(acc, 0.0f);
  }
}

// ---------------- CSR build ----------------
extern "C" __global__ void __launch_bounds__(256)
k_cnt(const int* __restrict__ ei, int* __restrict__ cnt) {
  const int e = blockIdx.x * blockDim.x + threadIdx.x;
  if (e < N_EDGES) atomicAdd(&cnt[ei[N_EDGES + e]], 1);
}

// single-block exclusive scan over 30000 counts -> row_ptr (rp) and write
// cursor copy (wptr)
extern "C" __global__ void __launch_bounds__(1024)
k_scan(const int* __restrict__ cnt, int* __restrict__ rp, int* __restrict__ wptr) {
  const int t = threadIdx.x;
  const int CH = (N_NODES + 1023) / 1024;  // 30
  int vals[CH];
  int s = 0;
#pragma unroll
  for (int k = 0; k < CH; ++k) {
    const int idx = t * CH + k;
    const int c = (idx < N_NODES) ? cnt[idx] : 0;
    vals[k] = s;
    s += c;
  }
  __shared__ int bs[1024];
  bs[t] = s;
  __syncthreads();
  for (int off = 1; off < 1024; off <<= 1) {
    int v = 0;
    if (t >= off) v = bs[t - off];
    __syncthreads();
    if (t >= off) bs[t] += v;
    __syncthreads();
  }
  const int prefix = (t == 0) ? 0 : bs[t - 1];
#pragma unroll
  for (int k = 0; k < CH; ++k) {
    const int idx = t * CH + k;
    if (idx < N_NODES) {
      rp[idx] = prefix + vals[k];
      wptr[idx] = prefix + vals[k];
    }
  }
  if (t == 1023) rp[N_NODES] = bs[1023];
}

extern "C" __global__ void __launch_bounds__(256)
k_scatter(const int* __restrict__ ei, int* __restrict__ wptr,
          int* __restrict__ srcs, int* __restrict__ eidx) {
  const int e = blockIdx.x * blockDim.x + threadIdx.x;
  if (e < N_EDGES) {
    const int d = ei[N_EDGES + e];
    const int pos = atomicAdd(&wptr[d], 1);
    srcs[pos] = ei[e];
    eidx[pos] = e;
  }
}

// ---------------- node projections ----------------
extern "C" __global__ void __launch_bounds__(256)
k_nodeproj(const float* __restrict__ h, const float* __restrict__ wf,
           const float* __restrict__ wsm, float* __restrict__ pf,
           float* __restrict__ ps) {
  const int lane = threadIdx.x & 63;
  const int w = threadIdx.x >> 6;  // 0..3
  const float* W = (w < 2) ? wf : wsm;
  const int roff = (w & 1) * 64;
  float wreg[D1];
#pragma unroll
  for (int k = 0; k < D1; ++k) wreg[k] = W[(size_t)(roff + k) * D1 + lane];
  float* out = (w < 2) ? pf : ps;
  const int ooff = (w & 1) * 64;
  for (int i = blockIdx.x; i < N_NODES; i += gridDim.x) {
    const float4* hr = (const float4*)(h + (size_t)i * D1);
    float acc = 0.0f;
#pragma unroll
    for (int k4 = 0; k4 < D1 / 4; ++k4) {
      const float4 v = hr[k4];
      acc = fmaf(v.x, wreg[4 * k4 + 0], acc);
      acc = fmaf(v.y, wreg[4 * k4 + 1], acc);
      acc = fmaf(v.z, wreg[4 * k4 + 2], acc);
      acc = fmaf(v.w, wreg[4 * k4 + 3], acc);
    }
    out[(size_t)i * 128 + ooff + lane] = acc;
  }
}

// ---------------- CSR edge kernel: wave per dst node ----------------
// af = pf[i].dst + pf[s].src + bf + ea[e] @ Wf2 ; as likewise with Ws2.
// m = sigmoid(af)*softplus(as); acc over node's edges; write mean (no atomics).
extern "C" __global__ void __launch_bounds__(256, 2)
k_edge2(const float* __restrict__ pf, const float* __restrict__ ps,
        const float* __restrict__ ea, const int* __restrict__ srcs,
        const int* __restrict__ eidx, const int* __restrict__ rp,
        const float* __restrict__ wf2, const float* __restrict__ ws2,
        const float* __restrict__ bfp, const float* __restrict__ bsp,
        float* __restrict__ aggr) {
  const int lane = threadIdx.x & 63;
  float wf[EFEAT], wsr[EFEAT];
#pragma unroll
  for (int k = 0; k < EFEAT; ++k) {
    wf[k] = wf2[k * D1 + lane];
    wsr[k] = ws2[k * D1 + lane];
  }
  // pin weights in VGPRs: opaque to rematerialization
#pragma unroll
  for (int k = 0; k < EFEAT; ++k) {
    asm volatile("" : "+v"(wf[k]), "+v"(wsr[k]));
  }
  const float bfj = bfp[lane], bsj = bsp[lane];
  const int wave0 = __builtin_amdgcn_readfirstlane(blockIdx.x * 4 + (threadIdx.x >> 6));
  const int nw = gridDim.x * 4;
  for (int i = wave0; i < N_NODES; i += nw) {
    const int start = rp[i];
    const int end = rp[i + 1];
    const float pfd = pf[(size_t)i * 128 + lane];
    const float psd = ps[(size_t)i * 128 + lane];
    float acc = 0.0f;
    for (int e = start; e < end; ++e) {
      const int s = srcs[e];
      const int ee = eidx[e];
      float af = pfd + pf[(size_t)s * 128 + 64 + lane] + bfj;
      float as = psd + ps[(size_t)s * 128 + 64 + lane] + bsj;
      const float2* row = (const float2*)(ea + (size_t)ee * EFEAT);
#pragma unroll
      for (int k = 0; k < EFEAT / 2; ++k) {
        const float2 v = row[k];
        af = fmaf(v.x, wf[2 * k], af);
        af = fmaf(v.y, wf[2 * k + 1], af);
        as = fmaf(v.x, wsr[2 * k], as);
        as = fmaf(v.y, wsr[2 * k + 1], as);
      }
      const float sg = __builtin_amdgcn_rcpf(1.0f + __expf(-af));
      const float sp = __logf(1.0f + __expf(as));
      acc += sg * sp;
    }
    const float inv = 1.0f / fmaxf((float)(end - start), 1.0f);
    aggr[(size_t)i * D1 + lane] = acc * inv;
  }
}

// ---------------- BN stats: per-feature sum / sumsq of aggr (already meaned) --
extern "C" __global__ void __launch_bounds__(256)
k_stats(const float* __restrict__ aggr, float* __restrict__ musum,
        float* __restrict__ sqsum) {
  const int j = threadIdx.x & 63;
  const int rid = (blockIdx.x * blockDim.x + threadIdx.x) >> 6;
  const int rstr = (gridDim.x * blockDim.x) >> 6;
  float s = 0.0f, sq = 0.0f;
  for (int i = rid; i < N_NODES; i += rstr) {
    const float v = aggr[(size_t)i * D1 + j];
    s += v;
    sq = fmaf(v, v, sq);
  }
  __shared__ float ls[256], lq[256];
  ls[threadIdx.x] = s;
  lq[threadIdx.x] = sq;
  __syncthreads();
  if (threadIdx.x < 64) {
    s = ls[j] + ls[64 + j] + ls[128 + j] + ls[192 + j];
    sq = lq[j] + lq[64 + j] + lq[128 + j] + lq[192 + j];
    atomicAdd(&musum[j], s);
    atomicAdd(&sqsum[j], sq);
  }
}

extern "C" __global__ void __launch_bounds__(64)
k_bnfin(const float* __restrict__ musum, const float* __restrict__ sqsum,
        const float* __restrict__ gamma, const float* __restrict__ beta,
        float* __restrict__ rs, float* __restrict__ sh) {
  const int j = threadIdx.x;
  const float mu = musum[j] * (1.0f / N_NODES);
  const float var = sqsum[j] * (1.0f / N_NODES) - mu * mu;
  const float r = gamma[j] * rsqrtf(var + BN_EPS);
  rs[j] = r;
  sh[j] = beta[j] - mu * r;
}

// ---------------- h = relu(h + bn(aggr)) ----------------
extern "C" __global__ void __launch_bounds__(256)
k_update(float* __restrict__ h, const float* __restrict__ aggr,
         const float* __restrict__ rs, const float* __restrict__ sh) {
  const size_t idx = (size_t)blockIdx.x * blockDim.x + threadIdx.x;
  if (idx >= (size_t)N_NODES * D1) return;
  const int j = (int)(idx & 63);
  const float bn = fmaf(aggr[idx], rs[j], sh[j]);
  h[idx] = fmaxf(h[idx] + bn, 0.0f);
}

// ---------------- global mean pool (atomic) ----------------
extern "C" __global__ void __launch_bounds__(256)
k_pool(const float* __restrict__ h, const int* __restrict__ batch,
       float* __restrict__ pooled, float* __restrict__ gcnt) {
  const int lane = threadIdx.x & 63;
  const int wave = (blockIdx.x * blockDim.x + threadIdx.x) >> 6;
  const int nw = (gridDim.x * blockDim.x) >> 6;
  for (int i = wave; i < N_NODES; i += nw) {
    const int b = batch[i];
    atomicAdd(&pooled[(size_t)b * D1 + lane], h[(size_t)i * D1 + lane]);
    if (lane == 0) atomicAdd(&gcnt[b], 1.0f);
  }
}

// ---------------- final MLP chain, one wave per graph ----------------
extern "C" __global__ void __launch_bounds__(64)
k_mlp(const float* __restrict__ pooled, const float* __restrict__ gcnt,
      const float* __restrict__ lin1_w, const float* __restrict__ lin1_b,
      const float* __restrict__ fc_w, const float* __restrict__ fc_b,
      const float* __restrict__ lin2_w, const float* __restrict__ lin2_b,
      float* __restrict__ out) {
  const int g = blockIdx.x;
  const int j = threadIdx.x;
  __shared__ float vin[D1];
  const float inv = 1.0f / fmaxf(gcnt[g], 1.0f);
  float v = pooled[(size_t)g * D1 + j] * inv;
  for (int layer = 0; layer < 3; ++layer) {
    vin[j] = v;
    __syncthreads();
    const float* W;
    const float* B;
    if (layer == 0) {
      W = lin1_w;
      B = lin1_b;
    } else {
      W = fc_w + (size_t)(layer - 1) * D1 * D1;
      B = fc_b + (size_t)(layer - 1) * D1;
    }
    float acc = B[j];
#pragma unroll 16
    for (int k = 0; k < D1; ++k) acc = fmaf(vin[k], W[k * D1 + j], acc);
    v = fmaxf(acc, 0.0f);
    __syncthreads();
  }
  float p = v * lin2_w[j];
#pragma unroll
  for (int off = 32; off > 0; off >>= 1) p += __shfl_down(p, off);
  if (j == 0) out[g] = p + lin2_b[0];
}

extern "C" void kernel_launch(void* const* d_in, const int* in_sizes, int n_in,
                              void* d_out, int out_size, void* d_ws, size_t ws_size,
                              hipStream_t stream) {
  const float* x        = (const float*)d_in[0];
  const float* ea       = (const float*)d_in[1];
  const float* lin0_w   = (const float*)d_in[2];
  const float* lin0_b   = (const float*)d_in[3];
  const float* conv_wf  = (const float*)d_in[4];
  const float* conv_bf  = (const float*)d_in[5];
  const float* conv_ws  = (const float*)d_in[6];
  const float* conv_bs  = (const float*)d_in[7];
  const float* bn_gamma = (const float*)d_in[8];
  const float* bn_beta  = (const float*)d_in[9];
  const float* lin1_w   = (const float*)d_in[10];
  const float* lin1_b   = (const float*)d_in[11];
  const float* fc_w     = (const float*)d_in[12];
  const float* fc_b     = (const float*)d_in[13];
  const float* lin2_w   = (const float*)d_in[14];
  const float* lin2_b   = (const float*)d_in[15];
  const int*   ei       = (const int*)d_in[16];
  const int*   batch    = (const int*)d_in[17];

  float* wsp = (float*)d_ws;
  float* h      = wsp;                          // N*64
  float* pf     = h + (size_t)N_NODES * 64;     // N*128
  float* ps     = pf + (size_t)N_NODES * 128;   // N*128
  float* aggr   = ps + (size_t)N_NODES * 128;   // N*64
  float* musum  = aggr + (size_t)N_NODES * 64;  // 64
  float* sqsum  = musum + 64;                   // 64
  float* rs     = sqsum + 64;                   // 64
  float* sh     = rs + 64;                      // 64
  float* pooled = sh + 64;                      // G*64
  float* gcnt   = pooled + (size_t)NG * 64;     // G
  int*   cnt    = (int*)(gcnt + NG);            // N
  int*   rp     = cnt + N_NODES;                // N+1
  int*   wptr   = rp + N_NODES + 1;             // N
  int*   srcs   = wptr + N_NODES;               // E
  int*   eidx   = srcs + N_EDGES;               // E

  hipMemsetAsync(cnt, 0, N_NODES * sizeof(int), stream);
  hipMemsetAsync(pooled, 0, (NG * D1 + NG) * sizeof(float), stream);

  k_lin0<<<256, 256, 0, stream>>>(x, lin0_w, lin0_b, h);
  k_cnt<<<(N_EDGES + 255) / 256, 256, 0, stream>>>(ei, cnt);
  k_scan<<<1, 1024, 0, stream>>>(cnt, rp, wptr);
  k_scatter<<<(N_EDGES + 255) / 256, 256, 0, stream>>>(ei, wptr, srcs, eidx);

  for (int l = 0; l < NL; ++l) {
    const float* wfl  = conv_wf + (size_t)l * ZD * D1;
    const float* wsl  = conv_ws + (size_t)l * ZD * D1;
    k_nodeproj<<<512, 256, 0, stream>>>(h, wfl, wsl, pf, ps);
    k_edge2<<<1875, 256, 0, stream>>>(pf, ps, ea, srcs, eidx, rp,
                                      wfl + 128 * D1, wsl + 128 * D1,
                                      conv_bf + (size_t)l * D1,
                                      conv_bs + (size_t)l * D1, aggr);
    hipMemsetAsync(musum, 0, 128 * sizeof(float), stream);
    k_stats<<<64, 256, 0, stream>>>(aggr, musum, sqsum);
    k_bnfin<<<1, 64, 0, stream>>>(musum, sqsum, bn_gamma + (size_t)l * D1,
                                  bn_beta + (size_t)l * D1, rs, sh);
    k_update<<<(N_NODES * D1 + 255) / 256, 256, 0, stream>>>(h, aggr, rs, sh);
  }

  k_pool<<<128, 256, 0, stream>>>(h, batch, pooled, gcnt);
  k_mlp<<<NG, 64, 0, stream>>>(pooled, gcnt, lin1_w, lin1_b, fc_w, fc_b,
                               lin2_w, lin2_b, (float*)d_out);
}